// Round 6
// baseline (209.890 us; speedup 1.0000x reference)
//
#include <hip/hip_runtime.h>
#include <hip/hip_bf16.h>
#include <stdint.h>
#include <math.h>

#define NROWS 16384
#define DHALF 384
#define DFULL 768
#define ROWB  384      // bytes per fp4 row: 768 elems * 4 bit
#define EPSF  1e-8f
#define QSCALE 64.0f   // N(0,0.036)*64 -> N(0,2.3): centered in e2m1 range +-6
#define NTILE (NROWS / 128)   // 128 tile-rows/cols

typedef __attribute__((ext_vector_type(4)))   float f32x4;
typedef __attribute__((ext_vector_type(16)))  float f32x16;
typedef __attribute__((ext_vector_type(4)))   int   int4v;
typedef __attribute__((ext_vector_type(8)))   int   int8v;

// ---- async global->LDS, 16B per lane (wave-uniform base + lane*16) ----
__device__ __forceinline__ void async_copy16(const void* gptr, void* lptr) {
    __builtin_amdgcn_global_load_lds(
        (const __attribute__((address_space(1))) unsigned int*)gptr,
        (__attribute__((address_space(3))) unsigned int*)lptr,
        16, 0, 0);
}

// monotone u32 from raw float bits (order-preserving for all finite floats)
__device__ __forceinline__ unsigned mono_bits(unsigned u) {
    return u ^ ((unsigned)(((int)u) >> 31) | 0x80000000u);
}

// float key: clear low 6 mantissa bits, embed 6-bit index. IEEE compare
// order == value order (perturbation <= 2^-18 relative, harmless after
// fp4 quantization); winner carries its index.
__device__ __forceinline__ float kf(float v, unsigned idx) {
    return __uint_as_float((__float_as_uint(v) & ~63u) | idx);
}

// float max with a DPP row_ror'd copy (16-lane row, pure VALU)
template <int CTRL>
__device__ __forceinline__ float fmax_ror(float v) {
    float t = __int_as_float(__builtin_amdgcn_update_dpp(
        0, __float_as_int(v), CTRL, 0xF, 0xF, false));
    return fmaxf(v, t);
}

// fp4 e2m1 encode, round-to-nearest: values {0,.5,1,1.5,2,3,4,6} (+sign)
__device__ __forceinline__ unsigned enc_fp4(float v) {
    float a = fabsf(v);
    unsigned c = (unsigned)(a >= 0.25f) + (a >= 0.75f) + (a >= 1.25f) +
                 (a >= 1.75f) + (a >= 2.5f) + (a >= 3.5f) + (a >= 5.0f);
    return c | (v < 0.0f ? 8u : 0u);
}

// fp32 -> bf16 bits, round-to-nearest-even (no NaN inputs here)
__device__ __forceinline__ unsigned f2bf(float f) {
    unsigned u = __float_as_uint(f);
    return (u + (((u >> 16) & 1u) + 0x7fffu)) >> 16;
}
__device__ __forceinline__ float bf_lo(unsigned w) {   // low bf16 of packed pair
    return __uint_as_float(w << 16);
}
__device__ __forceinline__ float bf_hi(unsigned w) {   // high bf16
    return __uint_as_float(w & 0xffff0000u);
}

// fp4 operand: HW reads only v[0:3] of the 8-reg tuple (cbsz/blgp=4).
// High half is compile-time zero — loads are 1x b128.
__device__ __forceinline__ int8v to8(int4v q) {
    int8v r;
    r[0] = q[0]; r[1] = q[1]; r[2] = q[2]; r[3] = q[3];
    r[4] = 0; r[5] = 0; r[6] = 0; r[7] = 0;
    return r;
}

// ---------------------------------------------------------------------
// Kernel 1: per-row L2 norm over concat(a,b); write fp4-e2m1 nibbles of
// (x_norm * 64). Optionally also write bf16 normalized rows (xb) for
// the loss gather. Zeroes best[row] (used by the atomic fallback path).
// ---------------------------------------------------------------------
__global__ __launch_bounds__(256) void normalize_kernel(
    const float* __restrict__ a, const float* __restrict__ b,
    unsigned char* __restrict__ xq, float* __restrict__ invn,
    unsigned long long* __restrict__ best,
    unsigned* __restrict__ xb) {           // nullable
    int wave = threadIdx.x >> 6;
    int lane = threadIdx.x & 63;
    int row  = blockIdx.x * 4 + wave;

    const float2* pa = (const float2*)(a + (size_t)row * DHALF);  // 192 pairs
    const float2* pb = (const float2*)(b + (size_t)row * DHALF);

    float2 va[3], vb[3];
    float s = 0.0f;
#pragma unroll
    for (int it = 0; it < 3; ++it) {
        va[it] = pa[lane + 64 * it];
        s += va[it].x * va[it].x + va[it].y * va[it].y;
    }
#pragma unroll
    for (int it = 0; it < 3; ++it) {
        vb[it] = pb[lane + 64 * it];
        s += vb[it].x * vb[it].x + vb[it].y * vb[it].y;
    }
#pragma unroll
    for (int d = 1; d < 64; d <<= 1) s += __shfl_xor(s, d, 64);

    float inv = 1.0f / fmaxf(sqrtf(s), EPSF);
    if (lane == 0) { invn[row] = inv; best[row] = 0ull; }
    float qs = inv * QSCALE;

    unsigned char* px = xq + (size_t)row * ROWB;
#pragma unroll
    for (int it = 0; it < 3; ++it)
        px[lane + 64 * it] =
            (unsigned char)(enc_fp4(va[it].x * qs) | (enc_fp4(va[it].y * qs) << 4));
#pragma unroll
    for (int it = 0; it < 3; ++it)
        px[192 + lane + 64 * it] =
            (unsigned char)(enc_fp4(vb[it].x * qs) | (enc_fp4(vb[it].y * qs) << 4));

    if (xb) {   // uniform branch
        unsigned* pw = xb + (size_t)row * (DFULL / 2);   // 384 packed pairs
#pragma unroll
        for (int it = 0; it < 3; ++it)
            pw[lane + 64 * it] =
                f2bf(va[it].x * inv) | (f2bf(va[it].y * inv) << 16);
#pragma unroll
        for (int it = 0; it < 3; ++it)
            pw[192 + lane + 64 * it] =
                f2bf(vb[it].x * inv) | (f2bf(vb[it].y * inv) << 16);
    }
}

// ---------------------------------------------------------------------
// Kernel 2: scaled dots via MX-fp4 32x32x64 MFMA (R16: was 16x16x128 —
// same FLOP/fragment bytes but HALF the MFMA instructions and the
// faster 32x32 pipe, 9099 vs 7228 TF ubench). 128x128 tile, 4 waves,
// each wave a 64x64 sub-tile of 2x2 32x32 frags. R11 2-buffer
// __syncthreads K-loop (counted-vmcnt measured slower, R14).
// R16 race fix: R15's cand plain-stores had TWO producers per
// (row, tile) — waves wc=0/1 (and wr=0/1 for cols) overwrote each
// other (nondeterministic, absmax 0.0019->0.0039). Winners now go to a
// 4 KB LDS buffer, one barrier, 128 threads combine halves and do the
// single external store (fallback: 128 atomics/block, was 512).
// ---------------------------------------------------------------------
__global__ __launch_bounds__(256, 4) void argmax_kernel(
    const unsigned char* __restrict__ xq,
    unsigned long long* __restrict__ best,
    unsigned long long* __restrict__ cand) {   // nullable -> atomic path
    __shared__ unsigned char As[2][128 * 64];
    __shared__ unsigned char Bs[2][128 * 64];
    __shared__ unsigned long long red[512];    // [0:256) rows, [256:512) cols

    // decode upper-triangle pair: k -> (rb <= cb)
    int k = blockIdx.x;
    int i = (int)((sqrtf(8.0f * (float)k + 1.0f) - 1.0f) * 0.5f);
    while ((i + 1) * (i + 2) / 2 <= k) ++i;
    while (i * (i + 1) / 2 > k) --i;
    int cb = i;
    int rb = k - i * (i + 1) / 2;   // rb <= cb
    int r0 = rb * 128, c0 = cb * 128;

    int tid  = threadIdx.x;
    int wave = tid >> 6, lane = tid & 63;
    int wr = wave >> 1, wc = wave & 1;
    int l31 = lane & 31, h = lane >> 5;

    f32x16 acc[2][2] = {};
    const int SC = 0x7f7f7f7f;      // e8m0 scales = 1.0 in every byte

    // staging pointers: 2 rounds x 256 threads cover 512 granules/tile
    const unsigned char* gA[2];
    const unsigned char* gB[2];
    int lofs[2];
#pragma unroll
    for (int r2 = 0; r2 < 2; ++r2) {
        int idx = r2 * 256 + tid;          // 0..511
        int r   = idx >> 2;                // 0..127
        int s   = idx & 3;                 // dst slot
        int g   = s ^ ((r ^ (r >> 2)) & 3);   // swizzled source granule
        gA[r2] = xq + (size_t)(r0 + r) * ROWB + (g << 4);
        gB[r2] = xq + (size_t)(c0 + r) * ROWB + (g << 4);
        lofs[r2] = idx * 16;
    }

    // fragment LDS offsets. 32x32x64 A/B layout: lane holds row (l&31),
    // k-chunk (ksub*32 + (l>>5)*... ) -> granule ga = ksub*2 + h, 16 B.
    // Write put source granule g at slot g ^ swz(row); swz(row) depends
    // only on ((lane ^ (lane>>2)) & 3) since row = base + (l&31), base
    // multiple of 32.
    int swzl = (lane ^ (lane >> 2)) & 3;
    int aof[2][2], bof[2][2];
#pragma unroll
    for (int ti = 0; ti < 2; ++ti)
#pragma unroll
        for (int ks = 0; ks < 2; ++ks) {
            int slot = ((ks * 2 + h) ^ swzl) << 4;
            aof[ti][ks] = (wr * 64 + ti * 32 + l31) * 64 + slot;
            bof[ti][ks] = (wc * 64 + ti * 32 + l31) * 64 + slot;
        }

    auto stage = [&](int k0b, int buf) {
        async_copy16(gA[0] + k0b, &As[buf][lofs[0]]);
        async_copy16(gA[1] + k0b, &As[buf][lofs[1]]);
        async_copy16(gB[0] + k0b, &Bs[buf][lofs[0]]);
        async_copy16(gB[1] + k0b, &Bs[buf][lofs[1]]);
    };
    auto compute = [&](int buf) {
        const unsigned char* Ab = As[buf];
        const unsigned char* Bb = Bs[buf];
        int8v af[2][2], bf[2][2];
#pragma unroll
        for (int t = 0; t < 2; ++t)
#pragma unroll
            for (int ks = 0; ks < 2; ++ks) {
                af[t][ks] = to8(*(const int4v*)(&Ab[aof[t][ks]]));
                bf[t][ks] = to8(*(const int4v*)(&Bb[bof[t][ks]]));
            }
#pragma unroll
        for (int ks = 0; ks < 2; ++ks)
#pragma unroll
            for (int ti = 0; ti < 2; ++ti)
#pragma unroll
                for (int tj = 0; tj < 2; ++tj)
                    acc[ti][tj] = __builtin_amdgcn_mfma_scale_f32_32x32x64_f8f6f4(
                        af[ti][ks], bf[tj][ks], acc[ti][tj], 4, 4, 0, SC, 0, SC);
    };

    stage(0, 0);
    __syncthreads();
    int buf = 0;
#pragma unroll 1
    for (int k0b = 64; k0b < ROWB; k0b += 64) {   // 5 pipelined steps
        stage(k0b, buf ^ 1);
        compute(buf);
        __syncthreads();
        buf ^= 1;
    }
    compute(buf);                // last tile; epilogue below

    // Diagonal mask: only diagonal blocks, only waves with wr==wc.
    // C/D layout: col = l&31, row = (reg&3) + 8*(reg>>2) + 4*h.
    if (rb == cb && wr == wc) {
#pragma unroll
        for (int reg = 0; reg < 16; ++reg) {
            int rl = (reg & 3) + 8 * (reg >> 2) + 4 * h;
            if (l31 == rl) { acc[0][0][reg] = -1.0e30f; acc[1][1][reg] = -1.0e30f; }
        }
    }

    // Row-direction: per (ti,reg) the 64 lanes hold 2 rows x 32 cols
    // (halves h=0/1). Key idx = (tj<<5)|l31 (local col in the wave's
    // 64-wide strip). Reduce 32 lanes: 4 DPP rors + xor16.
#pragma unroll
    for (int ti = 0; ti < 2; ++ti)
#pragma unroll
        for (int reg = 0; reg < 16; ++reg) {
            float fk = fmaxf(kf(acc[ti][0][reg], (unsigned)l31),
                             kf(acc[ti][1][reg], (unsigned)(32 | l31)));
            fk = fmax_ror<0x121>(fk);   // ror 1
            fk = fmax_ror<0x122>(fk);   // ror 2
            fk = fmax_ror<0x124>(fk);   // ror 4
            fk = fmax_ror<0x128>(fk);   // ror 8
            fk = fmaxf(fk, __shfl_xor(fk, 16, 64));
            if (l31 == 0) {
                unsigned kb = __float_as_uint(fk);
                int rl = ti * 32 + (reg & 3) + 8 * (reg >> 2) + 4 * h;
                red[wc * 128 + wr * 64 + rl] =
                    ((unsigned long long)(mono_bits(kb) & ~63u) << 32) |
                    (unsigned)(c0 + wc * 64 + (int)(kb & 63u));
            }
        }

    // Column-direction (off-diagonal blocks): 32 in-lane candidates per
    // tj (key idx = local row = ti*32+(reg&3)+8*(reg>>2)+4*h), then one
    // xor32 (lanes l and l+32 hold the same col).
    if (rb != cb) {
#pragma unroll
        for (int tj = 0; tj < 2; ++tj) {
            float fk = kf(acc[0][tj][0], (unsigned)(4 * h));
#pragma unroll
            for (int ti = 0; ti < 2; ++ti)
#pragma unroll
                for (int reg = 0; reg < 16; ++reg)
                    if (ti | reg)
                        fk = fmaxf(fk, kf(acc[ti][tj][reg],
                              (unsigned)(ti * 32 + (reg & 3) + 8 * (reg >> 2) + 4 * h)));
            fk = fmaxf(fk, __shfl_xor(fk, 32, 64));
            if (h == 0) {
                unsigned kb = __float_as_uint(fk);
                int cl = tj * 32 + l31;
                red[256 + wr * 128 + wc * 64 + cl] =
                    ((unsigned long long)(mono_bits(kb) & ~63u) << 32) |
                    (unsigned)(r0 + wr * 64 + (int)(kb & 63u));
            }
        }
    }

    __syncthreads();

    // Combine the two wave-halves; single external store per row/col.
    if (tid < 128) {
        unsigned long long g0 = red[tid], g1 = red[128 + tid];
        unsigned long long g = g0 > g1 ? g0 : g1;
        if (cand) cand[(size_t)cb * NROWS + r0 + tid] = g;
        else      atomicMax(&best[r0 + tid], g);
        if (rb != cb) {
            unsigned long long h0 = red[256 + tid], h1 = red[384 + tid];
            unsigned long long gg = h0 > h1 ? h0 : h1;
            if (cand) cand[(size_t)rb * NROWS + c0 + tid] = gg;
            else      atomicMax(&best[c0 + tid], gg);
        }
    }
}

// ---------------------------------------------------------------------
// Kernel 2b: best[r] = max over 128 tile-candidates cand[t][r].
// Coalesced: consecutive threads read consecutive r. 16.8 MB ~ 3 us.
// ---------------------------------------------------------------------
__global__ __launch_bounds__(256) void best_reduce_kernel(
    const unsigned long long* __restrict__ cand,
    unsigned long long* __restrict__ best) {
    int r = blockIdx.x * 256 + threadIdx.x;
    unsigned long long m = 0ull;
#pragma unroll 8
    for (int t = 0; t < NTILE; ++t) {
        unsigned long long v = cand[(size_t)t * NROWS + r];
        m = v > m ? v : m;
    }
    best[r] = m;
}

// ---------------------------------------------------------------------
// Kernel 3a: loss from bf16 normalized rows (50 MB vs 100 MB fp32 path)
// ---------------------------------------------------------------------
__global__ __launch_bounds__(256) void loss_bf16_kernel(
    const unsigned* __restrict__ xb,
    const unsigned long long* __restrict__ best,
    float* __restrict__ terms) {
    int wave = threadIdx.x >> 6;
    int lane = threadIdx.x & 63;
    int row  = blockIdx.x * 4 + wave;

    int j = (int)(best[row] & 0xffffffffull);
    const uint2* pi = (const uint2*)(xb + (size_t)row * (DFULL / 2));
    const uint2* pj = (const uint2*)(xb + (size_t)j   * (DFULL / 2));

    float s = 0.0f;
#pragma unroll
    for (int it = 0; it < 3; ++it) {
        int kk = lane + 64 * it;
        uint2 wi = pi[kk], wj = pj[kk];
        float d0 = bf_lo(wi.x) - bf_lo(wj.x) + EPSF;
        float d1 = bf_hi(wi.x) - bf_hi(wj.x) + EPSF;
        float d2 = bf_lo(wi.y) - bf_lo(wj.y) + EPSF;
        float d3 = bf_hi(wi.y) - bf_hi(wj.y) + EPSF;
        s += d0 * d0 + d1 * d1 + d2 * d2 + d3 * d3;
    }
#pragma unroll
    for (int d = 1; d < 64; d <<= 1) s += __shfl_xor(s, d, 64);

    if (lane == 0) terms[row] = logf(sqrtf(s) + EPSF);
}

// ---------------------------------------------------------------------
// Kernel 3b: fallback — loss from fp32 originals (if ws too small)
// ---------------------------------------------------------------------
__global__ __launch_bounds__(256) void loss_kernel(
    const float* __restrict__ a, const float* __restrict__ b,
    const float* __restrict__ invn,
    const unsigned long long* __restrict__ best,
    float* __restrict__ terms) {
    int wave = threadIdx.x >> 6;
    int lane = threadIdx.x & 63;
    int row  = blockIdx.x * 4 + wave;

    int j = (int)(best[row] & 0xffffffffull);
    float ii = invn[row], ij = invn[j];

    const float2* pai = (const float2*)(a + (size_t)row * DHALF);
    const float2* pbi = (const float2*)(b + (size_t)row * DHALF);
    const float2* paj = (const float2*)(a + (size_t)j * DHALF);
    const float2* pbj = (const float2*)(b + (size_t)j * DHALF);

    float s = 0.0f;
#pragma unroll
    for (int it = 0; it < 3; ++it) {
        int kk = lane + 64 * it;
        float2 di = pai[kk], dj = paj[kk];
        float dx = di.x * ii - dj.x * ij + EPSF;
        float dy = di.y * ii - dj.y * ij + EPSF;
        s += dx * dx + dy * dy;
    }
#pragma unroll
    for (int it = 0; it < 3; ++it) {
        int kk = lane + 64 * it;
        float2 di = pbi[kk], dj = pbj[kk];
        float dx = di.x * ii - dj.x * ij + EPSF;
        float dy = di.y * ii - dj.y * ij + EPSF;
        s += dx * dx + dy * dy;
    }
#pragma unroll
    for (int d = 1; d < 64; d <<= 1) s += __shfl_xor(s, d, 64);

    if (lane == 0) terms[row] = logf(sqrtf(s) + EPSF);
}

// ---------------------------------------------------------------------
// Kernel 4: single-block tree reduction of terms -> out[0] = -mean
// ---------------------------------------------------------------------
__global__ __launch_bounds__(1024) void reduce_kernel(
    const float* __restrict__ terms, float* __restrict__ out) {
    __shared__ float partial[16];
    int tid = threadIdx.x;
    float s = 0.0f;
#pragma unroll
    for (int it = 0; it < NROWS / 1024; ++it) s += terms[tid + 1024 * it];
#pragma unroll
    for (int d = 1; d < 64; d <<= 1) s += __shfl_xor(s, d, 64);
    if ((tid & 63) == 0) partial[tid >> 6] = s;
    __syncthreads();
    if (tid < 16) {
        s = partial[tid];
#pragma unroll
        for (int d = 1; d < 16; d <<= 1) s += __shfl_xor(s, d, 16);
        if (tid == 0) out[0] = -s * (1.0f / (float)NROWS);
    }
}

// ---------------------------------------------------------------------
extern "C" void kernel_launch(void* const* d_in, const int* in_sizes, int n_in,
                              void* d_out, int out_size, void* d_ws, size_t ws_size,
                              hipStream_t stream) {
    const float* a = (const float*)d_in[0];
    const float* b = (const float*)d_in[1];
    float* out = (float*)d_out;

    char* ws = (char*)d_ws;
    unsigned char* xq = (unsigned char*)ws;                                    // 6291456 B
    unsigned long long* best = (unsigned long long*)(ws + 6291456);            // 131072 B
    float* invn  = (float*)(ws + 6291456 + 131072);                            // 65536 B
    float* terms = (float*)(ws + 6291456 + 131072 + 65536);                    // 65536 B
    unsigned* xb = (unsigned*)(ws + 6553600);                                  // 25165824 B
    unsigned long long* cand = (unsigned long long*)(ws + 31719424);           // 16777216 B
    const size_t need_xb   = 31719424ull;
    const size_t need_cand = 48496640ull;
    const bool use_xb   = ws_size >= need_xb;     // constant across calls
    const bool use_cand = ws_size >= need_cand;   // constant across calls

    const int NBLK = NTILE * (NTILE + 1) / 2;          // 8256

    normalize_kernel<<<NROWS / 4, 256, 0, stream>>>(
        a, b, xq, invn, best, use_xb ? xb : (unsigned*)nullptr);
    argmax_kernel<<<NBLK, 256, 0, stream>>>(
        xq, best, use_cand ? cand : (unsigned long long*)nullptr);
    if (use_cand)
        best_reduce_kernel<<<NROWS / 256, 256, 0, stream>>>(cand, best);
    if (use_xb)
        loss_bf16_kernel<<<NROWS / 4, 256, 0, stream>>>(xb, best, terms);
    else
        loss_kernel<<<NROWS / 4, 256, 0, stream>>>(a, b, invn, best, terms);
    reduce_kernel<<<1, 1024, 0, stream>>>(terms, out);
}

// Round 7
// 193.308 us; speedup vs baseline: 1.0858x; 1.0858x over previous
//
#include <hip/hip_runtime.h>
#include <hip/hip_bf16.h>
#include <stdint.h>
#include <math.h>

#define NROWS 16384
#define DHALF 384
#define DFULL 768
#define ROWB  384      // bytes per fp4 row: 768 elems * 4 bit
#define EPSF  1e-8f
#define QSCALE 64.0f   // N(0,0.036)*64 -> N(0,2.3): centered in e2m1 range +-6
#define NTILE (NROWS / 128)   // 128 tile-rows/cols

typedef __attribute__((ext_vector_type(4)))  float f32x4;
typedef __attribute__((ext_vector_type(4)))  int   int4v;
typedef __attribute__((ext_vector_type(8)))  int   int8v;

// ---- async global->LDS, 16B per lane (wave-uniform base + lane*16) ----
__device__ __forceinline__ void async_copy16(const void* gptr, void* lptr) {
    __builtin_amdgcn_global_load_lds(
        (const __attribute__((address_space(1))) unsigned int*)gptr,
        (__attribute__((address_space(3))) unsigned int*)lptr,
        16, 0, 0);
}

// monotone u32 from raw float bits (order-preserving for all finite floats)
__device__ __forceinline__ unsigned mono_bits(unsigned u) {
    return u ^ ((unsigned)(((int)u) >> 31) | 0x80000000u);
}

// float key: clear low 6 mantissa bits, embed 6-bit index. IEEE compare
// order == value order (perturbation <= 2^-18 relative, harmless after
// fp4 quantization); winner carries its index.
__device__ __forceinline__ float kf(float v, unsigned idx) {
    return __uint_as_float((__float_as_uint(v) & ~63u) | idx);
}

// float max with a DPP row_ror'd copy (16-lane row, pure VALU)
template <int CTRL>
__device__ __forceinline__ float fmax_ror(float v) {
    float t = __int_as_float(__builtin_amdgcn_update_dpp(
        0, __float_as_int(v), CTRL, 0xF, 0xF, false));
    return fmaxf(v, t);
}

// fp4 e2m1 encode, round-to-nearest: values {0,.5,1,1.5,2,3,4,6} (+sign)
__device__ __forceinline__ unsigned enc_fp4(float v) {
    float a = fabsf(v);
    unsigned c = (unsigned)(a >= 0.25f) + (a >= 0.75f) + (a >= 1.25f) +
                 (a >= 1.75f) + (a >= 2.5f) + (a >= 3.5f) + (a >= 5.0f);
    return c | (v < 0.0f ? 8u : 0u);
}

// fp32 -> bf16 bits, round-to-nearest-even (no NaN inputs here)
__device__ __forceinline__ unsigned f2bf(float f) {
    unsigned u = __float_as_uint(f);
    return (u + (((u >> 16) & 1u) + 0x7fffu)) >> 16;
}
__device__ __forceinline__ float bf_lo(unsigned w) {   // low bf16 of packed pair
    return __uint_as_float(w << 16);
}
__device__ __forceinline__ float bf_hi(unsigned w) {   // high bf16
    return __uint_as_float(w & 0xffff0000u);
}

// fp4 operand: HW reads only v[0:3] of the 8-reg tuple (cbsz/blgp=4).
// High half is compile-time zero — loads are 1x b128.
__device__ __forceinline__ int8v to8(int4v q) {
    int8v r;
    r[0] = q[0]; r[1] = q[1]; r[2] = q[2]; r[3] = q[3];
    r[4] = 0; r[5] = 0; r[6] = 0; r[7] = 0;
    return r;
}

// ---------------------------------------------------------------------
// Kernel 1: per-row L2 norm over concat(a,b); write fp4-e2m1 nibbles of
// (x_norm * 64). Optionally also write bf16 normalized rows (xb) for
// the loss gather. Zeroes best[row] (used by the atomic fallback path).
// ---------------------------------------------------------------------
__global__ __launch_bounds__(256) void normalize_kernel(
    const float* __restrict__ a, const float* __restrict__ b,
    unsigned char* __restrict__ xq, float* __restrict__ invn,
    unsigned long long* __restrict__ best,
    unsigned* __restrict__ xb) {           // nullable
    int wave = threadIdx.x >> 6;
    int lane = threadIdx.x & 63;
    int row  = blockIdx.x * 4 + wave;

    const float2* pa = (const float2*)(a + (size_t)row * DHALF);  // 192 pairs
    const float2* pb = (const float2*)(b + (size_t)row * DHALF);

    float2 va[3], vb[3];
    float s = 0.0f;
#pragma unroll
    for (int it = 0; it < 3; ++it) {
        va[it] = pa[lane + 64 * it];
        s += va[it].x * va[it].x + va[it].y * va[it].y;
    }
#pragma unroll
    for (int it = 0; it < 3; ++it) {
        vb[it] = pb[lane + 64 * it];
        s += vb[it].x * vb[it].x + vb[it].y * vb[it].y;
    }
#pragma unroll
    for (int d = 1; d < 64; d <<= 1) s += __shfl_xor(s, d, 64);

    float inv = 1.0f / fmaxf(sqrtf(s), EPSF);
    if (lane == 0) { invn[row] = inv; best[row] = 0ull; }
    float qs = inv * QSCALE;

    unsigned char* px = xq + (size_t)row * ROWB;
#pragma unroll
    for (int it = 0; it < 3; ++it)
        px[lane + 64 * it] =
            (unsigned char)(enc_fp4(va[it].x * qs) | (enc_fp4(va[it].y * qs) << 4));
#pragma unroll
    for (int it = 0; it < 3; ++it)
        px[192 + lane + 64 * it] =
            (unsigned char)(enc_fp4(vb[it].x * qs) | (enc_fp4(vb[it].y * qs) << 4));

    if (xb) {   // uniform branch
        unsigned* pw = xb + (size_t)row * (DFULL / 2);   // 384 packed pairs
#pragma unroll
        for (int it = 0; it < 3; ++it)
            pw[lane + 64 * it] =
                f2bf(va[it].x * inv) | (f2bf(va[it].y * inv) << 16);
#pragma unroll
        for (int it = 0; it < 3; ++it)
            pw[192 + lane + 64 * it] =
                f2bf(vb[it].x * inv) | (f2bf(vb[it].y * inv) << 16);
    }
}

// ---------------------------------------------------------------------
// Kernel 2: scaled dots via MX-fp4 16x16x128 MFMA, 128x128 tile
// (R17: reverted from 32x32x64 — that shape doubled the epilogue's
// cross-lane reduction trees, +21 us of VALU; MFMA cycles were equal).
// R11 2-buffer __syncthreads K-loop (counted-vmcnt slower, R14).
// Race-free epilogue (R16 fix kept): wave winners -> red[] LDS, one
// barrier, 128 threads combine the two halves, single external store.
// NEW (T1): XCD-aware block swizzle — 8256 % 8 == 0, kk=(k&7)*1032+k/8
// gives each XCD a contiguous run of upper-triangle tiles so B-panels
// stay in its private L2 (R16 counters: 69 MB L2-miss refetch of a
// 6 MB input).
// ---------------------------------------------------------------------
__global__ __launch_bounds__(256, 4) void argmax_kernel(
    const unsigned char* __restrict__ xq,
    unsigned long long* __restrict__ best,
    unsigned long long* __restrict__ cand) {   // nullable -> atomic path
    __shared__ unsigned char As[2][128 * 64];
    __shared__ unsigned char Bs[2][128 * 64];
    __shared__ unsigned long long red[512];    // [0:256) rows, [256:512) cols

    // XCD swizzle (bijective: 8256 = 8 * 1032), then decode k -> (rb<=cb)
    int k = ((int)blockIdx.x & 7) * 1032 + ((int)blockIdx.x >> 3);
    int i = (int)((sqrtf(8.0f * (float)k + 1.0f) - 1.0f) * 0.5f);
    while ((i + 1) * (i + 2) / 2 <= k) ++i;
    while (i * (i + 1) / 2 > k) --i;
    int cb = i;
    int rb = k - i * (i + 1) / 2;   // rb <= cb
    int r0 = rb * 128, c0 = cb * 128;

    int tid  = threadIdx.x;
    int wave = tid >> 6, lane = tid & 63;
    int wr = wave >> 1, wc = wave & 1;
    int quad = lane >> 4, l15 = lane & 15;

    f32x4 acc[4][4] = {};
    const int SC = 0x7f7f7f7f;      // e8m0 scales = 1.0 in every byte

    // staging pointers: 2 rounds x 256 threads cover 512 granules/tile
    const unsigned char* gA[2];
    const unsigned char* gB[2];
    int lofs[2];
#pragma unroll
    for (int r2 = 0; r2 < 2; ++r2) {
        int idx = r2 * 256 + tid;          // 0..511
        int r   = idx >> 2;                // 0..127
        int s   = idx & 3;                 // dst slot
        int g   = s ^ ((r ^ (r >> 2)) & 3);   // swizzled source granule
        gA[r2] = xq + (size_t)(r0 + r) * ROWB + (g << 4);
        gB[r2] = xq + (size_t)(c0 + r) * ROWB + (g << 4);
        lofs[r2] = idx * 16;
    }

    // fragment LDS offsets (loop-invariant)
    int s0 = ((quad ^ ((l15 ^ (l15 >> 2)) & 3)) << 4);
    int aof[4], bof[4];
#pragma unroll
    for (int t = 0; t < 4; ++t) {
        aof[t] = (wr * 64 + t * 16 + l15) * 64 + s0;
        bof[t] = (wc * 64 + t * 16 + l15) * 64 + s0;
    }

    auto stage = [&](int k0b, int buf) {
        async_copy16(gA[0] + k0b, &As[buf][lofs[0]]);
        async_copy16(gA[1] + k0b, &As[buf][lofs[1]]);
        async_copy16(gB[0] + k0b, &Bs[buf][lofs[0]]);
        async_copy16(gB[1] + k0b, &Bs[buf][lofs[1]]);
    };
    auto compute = [&](int buf) {
        const unsigned char* Ab = As[buf];
        const unsigned char* Bb = Bs[buf];
        int8v bfr[4];
#pragma unroll
        for (int t = 0; t < 4; ++t)
            bfr[t] = to8(*(const int4v*)(&Bb[bof[t]]));
#pragma unroll
        for (int ti = 0; ti < 4; ++ti) {
            int8v a8 = to8(*(const int4v*)(&Ab[aof[ti]]));
#pragma unroll
            for (int tj = 0; tj < 4; ++tj)
                acc[ti][tj] = __builtin_amdgcn_mfma_scale_f32_16x16x128_f8f6f4(
                    a8, bfr[tj], acc[ti][tj], 4, 4, 0, SC, 0, SC);
        }
    };

    stage(0, 0);
    __syncthreads();
    int buf = 0;
#pragma unroll 1
    for (int k0b = 64; k0b < ROWB; k0b += 64) {   // 5 pipelined steps
        stage(k0b, buf ^ 1);
        compute(buf);
        __syncthreads();
        buf ^= 1;
    }
    compute(buf);                // last tile; epilogue below

    int rbase = r0 + wr * 64, cbase = c0 + wc * 64;

    // Diagonal mask: only possible in diagonal blocks, and only in waves
    // with wr==wc. Hoisted here so the hot epilogue below is mask-free.
    if (rb == cb && wr == wc) {
#pragma unroll
        for (int ti = 0; ti < 4; ++ti)
#pragma unroll
            for (int reg = 0; reg < 4; ++reg)
                if (l15 == quad * 4 + reg)
                    acc[ti][ti][reg] = -1.0e30f;
    }

    // Row-direction: float key = (bits & ~63) | (tj<<4 | l15); fmax + DPP
    // reduce; monotone transform once on the 16-lane winner. Winner ->
    // red[wc*128 + local_row] (each wc half has exactly one producer).
#pragma unroll
    for (int ti = 0; ti < 4; ++ti) {
#pragma unroll
        for (int reg = 0; reg < 4; ++reg) {
            float f0 = kf(acc[ti][0][reg], (unsigned)((0 << 4) | l15));
            float f1 = kf(acc[ti][1][reg], (unsigned)((1 << 4) | l15));
            float f2 = kf(acc[ti][2][reg], (unsigned)((2 << 4) | l15));
            float f3 = kf(acc[ti][3][reg], (unsigned)((3 << 4) | l15));
            float fk = fmaxf(fmaxf(f0, f1), fmaxf(f2, f3));
            fk = fmax_ror<0x121>(fk);   // ror 1
            fk = fmax_ror<0x122>(fk);   // ror 2
            fk = fmax_ror<0x124>(fk);   // ror 4
            fk = fmax_ror<0x128>(fk);   // ror 8
            if (l15 == 0) {
                unsigned kb = __float_as_uint(fk);
                int rl  = wr * 64 + ti * 16 + quad * 4 + reg;   // local row
                int col = cbase + (int)(((kb >> 4) & 3u) * 16u + (kb & 15u));
                red[wc * 128 + rl] =
                    ((unsigned long long)(mono_bits(kb) & ~63u) << 32) |
                    (unsigned)col;
            }
        }
    }

    // Column-direction (off-diagonal blocks): 16 in-lane candidates,
    // then 2 cross-lane maxes; key idx = (ti<<4)|(quad<<2)|reg.
    // Winner -> red[256 + wr*128 + local_col].
    if (rb != cb) {
#pragma unroll
        for (int tj = 0; tj < 4; ++tj) {
            float fk = kf(acc[0][tj][0], (unsigned)(quad << 2));
#pragma unroll
            for (int ti = 0; ti < 4; ++ti)
#pragma unroll
                for (int reg = 0; reg < 4; ++reg)
                    if (ti | reg)
                        fk = fmaxf(fk, kf(acc[ti][tj][reg],
                                (unsigned)((ti << 4) | (quad << 2) | reg)));
            fk = fmaxf(fk, __shfl_xor(fk, 16, 64));
            fk = fmaxf(fk, __shfl_xor(fk, 32, 64));
            if (quad == 0) {
                unsigned kb = __float_as_uint(fk);
                int grow = rbase + (int)(((kb >> 4) & 3u) * 16u +
                                         ((kb >> 2) & 3u) * 4u + (kb & 3u));
                int cl   = wc * 64 + tj * 16 + l15;   // local col
                red[256 + wr * 128 + cl] =
                    ((unsigned long long)(mono_bits(kb) & ~63u) << 32) |
                    (unsigned)grow;
            }
        }
    }

    __syncthreads();

    // Combine the two halves; single external store per row/col.
    if (tid < 128) {
        unsigned long long g0 = red[tid], g1 = red[128 + tid];
        unsigned long long g = g0 > g1 ? g0 : g1;
        if (cand) cand[(size_t)cb * NROWS + r0 + tid] = g;
        else      atomicMax(&best[r0 + tid], g);
        if (rb != cb) {
            unsigned long long h0 = red[256 + tid], h1 = red[384 + tid];
            unsigned long long gg = h0 > h1 ? h0 : h1;
            if (cand) cand[(size_t)rb * NROWS + c0 + tid] = gg;
            else      atomicMax(&best[c0 + tid], gg);
        }
    }
}

// ---------------------------------------------------------------------
// Kernel 2b: best[r] = max over 128 tile-candidates cand[t][r].
// Coalesced: consecutive threads read consecutive r. 16.8 MB ~ 3 us.
// ---------------------------------------------------------------------
__global__ __launch_bounds__(256) void best_reduce_kernel(
    const unsigned long long* __restrict__ cand,
    unsigned long long* __restrict__ best) {
    int r = blockIdx.x * 256 + threadIdx.x;
    unsigned long long m = 0ull;
#pragma unroll 8
    for (int t = 0; t < NTILE; ++t) {
        unsigned long long v = cand[(size_t)t * NROWS + r];
        m = v > m ? v : m;
    }
    best[r] = m;
}

// ---------------------------------------------------------------------
// Kernel 3a: loss from bf16 normalized rows (50 MB vs 100 MB fp32 path)
// ---------------------------------------------------------------------
__global__ __launch_bounds__(256) void loss_bf16_kernel(
    const unsigned* __restrict__ xb,
    const unsigned long long* __restrict__ best,
    float* __restrict__ terms) {
    int wave = threadIdx.x >> 6;
    int lane = threadIdx.x & 63;
    int row  = blockIdx.x * 4 + wave;

    int j = (int)(best[row] & 0xffffffffull);
    const uint2* pi = (const uint2*)(xb + (size_t)row * (DFULL / 2));
    const uint2* pj = (const uint2*)(xb + (size_t)j   * (DFULL / 2));

    float s = 0.0f;
#pragma unroll
    for (int it = 0; it < 3; ++it) {
        int kk = lane + 64 * it;
        uint2 wi = pi[kk], wj = pj[kk];
        float d0 = bf_lo(wi.x) - bf_lo(wj.x) + EPSF;
        float d1 = bf_hi(wi.x) - bf_hi(wj.x) + EPSF;
        float d2 = bf_lo(wi.y) - bf_lo(wj.y) + EPSF;
        float d3 = bf_hi(wi.y) - bf_hi(wj.y) + EPSF;
        s += d0 * d0 + d1 * d1 + d2 * d2 + d3 * d3;
    }
#pragma unroll
    for (int d = 1; d < 64; d <<= 1) s += __shfl_xor(s, d, 64);

    if (lane == 0) terms[row] = logf(sqrtf(s) + EPSF);
}

// ---------------------------------------------------------------------
// Kernel 3b: fallback — loss from fp32 originals (if ws too small)
// ---------------------------------------------------------------------
__global__ __launch_bounds__(256) void loss_kernel(
    const float* __restrict__ a, const float* __restrict__ b,
    const float* __restrict__ invn,
    const unsigned long long* __restrict__ best,
    float* __restrict__ terms) {
    int wave = threadIdx.x >> 6;
    int lane = threadIdx.x & 63;
    int row  = blockIdx.x * 4 + wave;

    int j = (int)(best[row] & 0xffffffffull);
    float ii = invn[row], ij = invn[j];

    const float2* pai = (const float2*)(a + (size_t)row * DHALF);
    const float2* pbi = (const float2*)(b + (size_t)row * DHALF);
    const float2* paj = (const float2*)(a + (size_t)j * DHALF);
    const float2* pbj = (const float2*)(b + (size_t)j * DHALF);

    float s = 0.0f;
#pragma unroll
    for (int it = 0; it < 3; ++it) {
        int kk = lane + 64 * it;
        float2 di = pai[kk], dj = paj[kk];
        float dx = di.x * ii - dj.x * ij + EPSF;
        float dy = di.y * ii - dj.y * ij + EPSF;
        s += dx * dx + dy * dy;
    }
#pragma unroll
    for (int it = 0; it < 3; ++it) {
        int kk = lane + 64 * it;
        float2 di = pbi[kk], dj = pbj[kk];
        float dx = di.x * ii - dj.x * ij + EPSF;
        float dy = di.y * ii - dj.y * ij + EPSF;
        s += dx * dx + dy * dy;
    }
#pragma unroll
    for (int d = 1; d < 64; d <<= 1) s += __shfl_xor(s, d, 64);

    if (lane == 0) terms[row] = logf(sqrtf(s) + EPSF);
}

// ---------------------------------------------------------------------
// Kernel 4: single-block tree reduction of terms -> out[0] = -mean
// ---------------------------------------------------------------------
__global__ __launch_bounds__(1024) void reduce_kernel(
    const float* __restrict__ terms, float* __restrict__ out) {
    __shared__ float partial[16];
    int tid = threadIdx.x;
    float s = 0.0f;
#pragma unroll
    for (int it = 0; it < NROWS / 1024; ++it) s += terms[tid + 1024 * it];
#pragma unroll
    for (int d = 1; d < 64; d <<= 1) s += __shfl_xor(s, d, 64);
    if ((tid & 63) == 0) partial[tid >> 6] = s;
    __syncthreads();
    if (tid < 16) {
        s = partial[tid];
#pragma unroll
        for (int d = 1; d < 16; d <<= 1) s += __shfl_xor(s, d, 16);
        if (tid == 0) out[0] = -s * (1.0f / (float)NROWS);
    }
}

// ---------------------------------------------------------------------
extern "C" void kernel_launch(void* const* d_in, const int* in_sizes, int n_in,
                              void* d_out, int out_size, void* d_ws, size_t ws_size,
                              hipStream_t stream) {
    const float* a = (const float*)d_in[0];
    const float* b = (const float*)d_in[1];
    float* out = (float*)d_out;

    char* ws = (char*)d_ws;
    unsigned char* xq = (unsigned char*)ws;                                    // 6291456 B
    unsigned long long* best = (unsigned long long*)(ws + 6291456);            // 131072 B
    float* invn  = (float*)(ws + 6291456 + 131072);                            // 65536 B
    float* terms = (float*)(ws + 6291456 + 131072 + 65536);                    // 65536 B
    unsigned* xb = (unsigned*)(ws + 6553600);                                  // 25165824 B
    unsigned long long* cand = (unsigned long long*)(ws + 31719424);           // 16777216 B
    const size_t need_xb   = 31719424ull;
    const size_t need_cand = 48496640ull;
    const bool use_xb   = ws_size >= need_xb;     // constant across calls
    const bool use_cand = ws_size >= need_cand;   // constant across calls

    const int NBLK = NTILE * (NTILE + 1) / 2;          // 8256

    normalize_kernel<<<NROWS / 4, 256, 0, stream>>>(
        a, b, xq, invn, best, use_xb ? xb : (unsigned*)nullptr);
    argmax_kernel<<<NBLK, 256, 0, stream>>>(
        xq, best, use_cand ? cand : (unsigned long long*)nullptr);
    if (use_cand)
        best_reduce_kernel<<<NROWS / 256, 256, 0, stream>>>(cand, best);
    if (use_xb)
        loss_bf16_kernel<<<NROWS / 4, 256, 0, stream>>>(xb, best, terms);
    else
        loss_kernel<<<NROWS / 4, 256, 0, stream>>>(a, b, invn, best, terms);
    reduce_kernel<<<1, 1024, 0, stream>>>(terms, out);
}